// Round 7
// baseline (26.976 us; speedup 1.0000x reference)
//
#include <hip/hip_runtime.h>
#include <math.h>

// Duhamel layer == per-channel causal FIR with h[q] = (1/wD) r^q sin(q*theta).
// Single-stream form: e[k] = (x[k] - g^W x[k-W])/wD;  Z = g*Z + e[k];
// y[n] = Im(Z[n]).  Per-thread global quad loads (no staging), IIR -> ly in
// LDS, wave affine scan for exact seeds, seeds parked in LDS pad slots,
// correction fused into the coalesced store via a per-thread g^{j0+u} table.

#define N_SAMP  65536
#define NB      16
#define NO      8
#define SPAN    8192
#define NT      512
#define LSEG    16

// Static FIR lengths (exact replica of reference VALID_W):
constexpr int CW[NO]  = {1844, 1317, 1024, 768, 576, 419, 307, 230};
// Halo: ceil(7/alpha) rounded to 32 (seed error e^-7 ~ 9e-4 relative).
constexpr int CHH[NO] = {2816, 2016, 1568, 1184, 896, 640, 480, 352};
// chunks = ceil(65536/(8192-H)) = {13,11,10,10,9,9,9,9}; prefix totals 80.

#define LDSY  (SPAN + ((SPAN) >> 5) * 4)   // 9216 floats = 36,864 B

// logical 32-group g -> physical [36g, 36g+32); slots 36g+32..35 are spare
__device__ __forceinline__ int pidx4(int i) { return i + ((i >> 5) << 2); }
// seed slot for owner thread T (uses the spare slots; 2 floats each)
__device__ __forceinline__ int sslot(int T) { return 36 * (T >> 1) + 32 + ((T & 1) << 1); }

__device__ __forceinline__ float rfl(float x) {
    return __int_as_float(__builtin_amdgcn_readfirstlane(__float_as_int(x)));
}

template<int O>
__device__ __forceinline__ void duh_run(const float* __restrict__ xg,
                                        const float* __restrict__ logw,
                                        float* __restrict__ out,
                                        float* __restrict__ lds_y,
                                        float (* __restrict__ wtot)[2],
                                        int c, int b)
{
    constexpr int W    = CW[O];
    constexpr int H    = CHH[O];
    constexpr int L    = SPAN - H;
    constexpr int OUT_T0 = H / LSEG;
    constexpr int D    = (4 - (W & 3)) & 3;  // (-W) mod 4: aligned-quad shift
    constexpr int NQH  = (D == 0) ? 2 : 3;   // delayed-stream quads per 8 samples

    const int n0   = c * L;
    const int t    = threadIdx.x;
    const int lane = t & 63;
    const int wv   = t >> 6;

    // ------- per-channel constants (fast HW transcendentals) -> SGPR --------
    const float XIf = 0.05f, DTf = 0.01f;
    const float omf  = fminf(fmaxf(__expf(logw[O]), 0.01f), 1000.0f);
    const float omD  = omf * sqrtf(1.0f - XIf * XIf);
    const float th   = omD * DTf;
    const float alph = XIf * omf * DTf;

    const float r1 = __expf(-alph);
    const float gr = rfl(r1 * __cosf(th)), gi = rfl(r1 * __sinf(th));    // g

    const float rW   = __expf(-alph * (float)W);
    const float aW   = th * (float)W;
    const float binv = rfl(1.0f / omD);
    const float sWr  = rfl(rW * __cosf(aW));                  // Re g^W
    const float cei  = rfl(-binv * rW * __sinf(aW));          // -Im(g^W)/wD

    float Mr[7], Mi[7];                                        // M[k]=g^(16*2^k)
    {
        const float rl = __expf(-alph * (float)LSEG);
        const float al = th * (float)LSEG;
        float pr = rl * __cosf(al), pq = rl * __sinf(al);
#pragma unroll
        for (int k = 0; k < 7; ++k) {
            Mr[k] = rfl(pr); Mi[k] = rfl(pq);
            const float nr = pr * pr - pq * pq;
            const float ni = 2.0f * pr * pq;
            pr = nr; pq = ni;
        }
    }
    // small powers of g for the fused-store rotation table
    const float g2r = rfl(gr * gr - gi * gi), g2i = rfl(2.0f * gr * gi);
    const float g3r = rfl(g2r * gr - g2i * gi), g3i = rfl(g2r * gi + g2i * gr);
    const float g4r = rfl(g3r * gr - g3i * gi), g4i = rfl(g3r * gi + g3i * gr);
    const float g8r = rfl(g4r * g4r - g4i * g4i), g8i = rfl(2.0f * g4r * g4i);

    // ---------------- phase A: per-thread global loads + IIR, ly -> LDS -----
    const float* xb = xg + (size_t)b * N_SAMP;
    const int s1g = (n0 - H) + (t << 4);      // stream-1 base (mult of 16)
    const int s2g = s1g - W - D;              // delayed-stream base (mult of 4)
    const int kb  = pidx4(t << 4);            // this thread's LDS base

    float Br = 0.f, Bi = 0.f;
#pragma unroll
    for (int h = 0; h < 2; ++h) {
        float s1[8];
#pragma unroll
        for (int m = 0; m < 2; ++m) {
            const int g = s1g + 4 * (2 * h + m);
            float4 q;
            if (g >= 0 && g < N_SAMP) {       // g mult of 4 -> whole quad ok
                q = *(const float4*)(xb + g);
            } else {
                q.x = (g + 0 >= 0 && g + 0 < N_SAMP) ? xb[g + 0] : 0.0f;
                q.y = (g + 1 >= 0 && g + 1 < N_SAMP) ? xb[g + 1] : 0.0f;
                q.z = (g + 2 >= 0 && g + 2 < N_SAMP) ? xb[g + 2] : 0.0f;
                q.w = (g + 3 >= 0 && g + 3 < N_SAMP) ? xb[g + 3] : 0.0f;
            }
            s1[4*m+0] = q.x; s1[4*m+1] = q.y; s1[4*m+2] = q.z; s1[4*m+3] = q.w;
        }
        float s2[8];
#pragma unroll
        for (int mm = 0; mm < NQH; ++mm) {
            const int m = 2 * h + mm;
            const int g = s2g + 4 * m;        // mult of 4
            float4 q;
            if (g >= 0 && g < N_SAMP) {
                q = *(const float4*)(xb + g);
            } else {
                q.x = (g + 0 >= 0 && g + 0 < N_SAMP) ? xb[g + 0] : 0.0f;
                q.y = (g + 1 >= 0 && g + 1 < N_SAMP) ? xb[g + 1] : 0.0f;
                q.z = (g + 2 >= 0 && g + 2 < N_SAMP) ? xb[g + 2] : 0.0f;
                q.w = (g + 3 >= 0 && g + 3 < N_SAMP) ? xb[g + 3] : 0.0f;
            }
#pragma unroll
            for (int u = 0; u < 4; ++u) {
                const int idx = 4 * m + u - D - 8 * h;
                if (idx >= 0 && idx < 8)
                    s2[idx] = (u == 0) ? q.x : (u == 1) ? q.y : (u == 2) ? q.z : q.w;
            }
        }
#pragma unroll
        for (int m = 0; m < 2; ++m) {
            float4 yq;
#pragma unroll
            for (int u = 0; u < 4; ++u) {
                const int j = 4 * m + u;
                const float a  = s1[j];
                const float cc = s2[j];
                const float er = binv * fmaf(-sWr, cc, a);  // Re e
                const float ei = cei * cc;                  // Im e
                const float nr = fmaf(gr, Br, fmaf(-gi, Bi, er));
                const float ni = fmaf(gi, Br, fmaf( gr, Bi, ei));
                Br = nr; Bi = ni;
                ((float*)&yq)[u] = Bi;
            }
            if (t >= OUT_T0)   // halo-only threads feed the scan, not ly
                *(float4*)&lds_y[kb + 8 * h + 4 * m] = yq;
        }
    }

    // ---------------- wave-level inclusive affine scan ----------------------
    float Sr = Br, Si = Bi;
#pragma unroll
    for (int k = 0; k < 6; ++k) {
        const int d = 1 << k;
        const float ur = __shfl_up(Sr, d, 64);
        const float ui = __shfl_up(Si, d, 64);
        if (lane >= d) {
            const float nr = fmaf(Mr[k], ur, fmaf(-Mi[k], ui, Sr));
            const float ni = fmaf(Mr[k], ui, fmaf( Mi[k], ur, Si));
            Sr = nr; Si = ni;
        }
    }
    if (lane == 63) { wtot[wv][0] = Sr; wtot[wv][1] = Si; }
    __syncthreads();

    // cross-wave carry (multiplier g^1024 = M[6])
    float cr = 0.f, ci = 0.f;
    for (int w2 = 0; w2 < wv; ++w2) {
        const float tr = wtot[w2][0], ti = wtot[w2][1];
        const float nr = fmaf(Mr[6], cr, fmaf(-Mi[6], ci, tr));
        const float ni = fmaf(Mr[6], ci, fmaf( Mi[6], cr, ti));
        cr = nr; ci = ni;
    }

    // exclusive in-wave prefix
    float pr_ = __shfl_up(Sr, 1, 64);
    float pi_ = __shfl_up(Si, 1, 64);
    if (lane == 0) { pr_ = 0.f; pi_ = 0.f; }

    // m^lane (product over set bits of lane)
    float plr = 1.f, pli = 0.f;
#pragma unroll
    for (int k = 0; k < 6; ++k) {
        if ((lane >> k) & 1) {
            const float nr = plr * Mr[k] - pli * Mi[k];
            const float ni = plr * Mi[k] + pli * Mr[k];
            plr = nr; pli = ni;
        }
    }
    // seed entering this thread's segment: u = p + m^lane * carry
    const float ur_ = fmaf(plr, cr, fmaf(-pli, ci, pr_));
    const float ui_ = fmaf(plr, ci, fmaf( pli, cr, pi_));

    // park seed in this thread's spare LDS slot
    const int sw = sslot(t);
    lds_y[sw]     = ur_;
    lds_y[sw + 1] = ui_;
    __syncthreads();

    // ---------------- fused correction + coalesced store --------------------
    // j0 = 4*(t&3) is each store-thread's fixed in-segment offset
    // (stride 2048 == 0 mod 16).  Rotation table G[u] = g^{j0+u+1}.
    const int tb = t & 3;
    float wr = 1.f, wi = 0.f;
    if (tb & 1) { wr = g4r; wi = g4i; }
    if (tb & 2) {
        const float nr = fmaf(wr, g8r, -(wi * g8i));
        const float ni = fmaf(wr, g8i,  (wi * g8r));
        wr = nr; wi = ni;
    }
    const float G0r = fmaf(gr,  wr, -(gi  * wi)), G0i = fmaf(gr,  wi,  gi  * wr);
    const float G1r = fmaf(g2r, wr, -(g2i * wi)), G1i = fmaf(g2r, wi,  g2i * wr);
    const float G2r = fmaf(g3r, wr, -(g3i * wi)), G2i = fmaf(g3r, wi,  g3i * wr);
    const float G3r = fmaf(g4r, wr, -(g4i * wi)), G3i = fmaf(g4r, wi,  g4i * wr);

    const int kmax = (n0 + L <= N_SAMP) ? L : (N_SAMP - n0);
    float* op = out + ((size_t)(b * NO + O)) * (size_t)N_SAMP + n0;
    for (int k = 4 * t; k < kmax; k += 4 * NT) {
        const int s = H + k;                       // quad stays in one segment
        const float4 lyq = *(const float4*)&lds_y[pidx4(s)];
        const int sa = sslot(s >> 4);
        const float ur = lds_y[sa], ui = lds_y[sa + 1];
        float4 yq;
        yq.x = fmaf(G0i, ur, fmaf(G0r, ui, lyq.x));
        yq.y = fmaf(G1i, ur, fmaf(G1r, ui, lyq.y));
        yq.z = fmaf(G2i, ur, fmaf(G2r, ui, lyq.z));
        yq.w = fmaf(G3i, ur, fmaf(G3r, ui, lyq.w));
        *(float4*)(op + k) = yq;
    }
}

__global__ __launch_bounds__(NT, 8)
void duh_kernel(const float* __restrict__ x, const float* __restrict__ logw,
                float* __restrict__ out)
{
    __shared__ float lds_y[LDSY];
    __shared__ float wtot[8][2];
    const int cid = blockIdx.x;
    const int b   = blockIdx.y;
    if      (cid < 13) duh_run<0>(x, logw, out, lds_y, wtot, cid,      b);
    else if (cid < 24) duh_run<1>(x, logw, out, lds_y, wtot, cid - 13, b);
    else if (cid < 34) duh_run<2>(x, logw, out, lds_y, wtot, cid - 24, b);
    else if (cid < 44) duh_run<3>(x, logw, out, lds_y, wtot, cid - 34, b);
    else if (cid < 53) duh_run<4>(x, logw, out, lds_y, wtot, cid - 44, b);
    else if (cid < 62) duh_run<5>(x, logw, out, lds_y, wtot, cid - 53, b);
    else if (cid < 71) duh_run<6>(x, logw, out, lds_y, wtot, cid - 62, b);
    else               duh_run<7>(x, logw, out, lds_y, wtot, cid - 71, b);
}

extern "C" void kernel_launch(void* const* d_in, const int* in_sizes, int n_in,
                              void* d_out, int out_size, void* d_ws, size_t ws_size,
                              hipStream_t stream) {
    const float* x  = (const float*)d_in[0];
    const float* lw = (const float*)d_in[1];
    float* out = (float*)d_out;

    dim3 grid(80, NB);   // 80 chunk-slots x 16 batches = 1280 blocks
    duh_kernel<<<grid, dim3(NT), 0, stream>>>(x, lw, out);
}